// Round 4
// baseline (335.140 us; speedup 1.0000x reference)
//
#include <hip/hip_runtime.h>

#define K0 3072
#define BPB 16            // batch rows per block
#define BLOCK 1024        // 16 waves: wave = (r<<3) | chunk

struct KtreeArgs {
  const float* x;
  const float* ap1; const float* ap2; const float* am1; const float* am2; const float* g0;
  const float* w[11];
  const float* bs[11];
  const float* root_w; const float* root_b;
  float* out;
};

__device__ __forceinline__ float lrelu(float v) {
  return v >= 0.0f ? v : 0.01f * v;
}

__device__ __forceinline__ int bitrev(int v, int bits) {
  int r = 0;
  for (int i = 0; i < bits; ++i) r |= ((v >> i) & 1) << (bits - 1 - i);
  return r;
}

__global__ __launch_bounds__(BLOCK, 8) void ktree_synapse_kernel(KtreeArgs A) {
  const int tid = threadIdx.x;
  const int wv  = tid >> 6;        // 0..15
  const int l   = tid & 63;
  const int c   = wv & 7;          // k-chunk: K=8-level node index
  const int r   = wv >> 3;         // population 0/1

  // bit-reversed placement: lane l owns K=512-level node c*64 + rev6(l),
  // so levels 2..7 reduce with single shfl_down per level (stride 32..1).
  const int r6      = bitrev(l, 6);
  const int node512 = c * 64 + r6;
  const int kb      = node512 * 6;          // 6 consecutive k per lane

  // ---- per-lane param pointers (reloaded per row; L1-resident) ----
  const int o_syn = r * K0 + kb;
  const float* p_ap1 = A.ap1 + o_syn;
  const float* p_ap2 = A.ap2 + o_syn;
  const float* p_am1 = A.am1 + o_syn;
  const float* p_am2 = A.am2 + o_syn;
  const float* p_g0  = A.g0  + o_syn;

  float w0v[6], b0a, b0b;
  {
    const int o = (r * 1024 + 2 * node512) * 3;
    #pragma unroll
    for (int j = 0; j < 6; ++j) w0v[j] = A.w[0][o + j];
    b0a = A.bs[0][r * 1024 + 2 * node512];
    b0b = A.bs[0][r * 1024 + 2 * node512 + 1];
  }
  float w1a, w1b, b1v;
  {
    const int n = r * 512 + node512;
    w1a = A.w[1][n * 2 + 0];
    w1b = A.w[1][n * 2 + 1];
    b1v = A.bs[1][n];
  }
  // levels 2..7 (shuffle levels), step s=0..5: pair-reduce with shfl_down
  float ws0[6], ws1[6], bsv[6];
  #pragma unroll
  for (int s = 0; s < 6; ++s) {
    const int active = (l < (64 >> (s + 1)));
    const int local  = active ? bitrev(l, 5 - s) : 0;   // parent node within chunk
    const int ktot   = 256 >> s;                        // nodes per r at out level
    const int m      = r * ktot + c * (32 >> s) + local;
    ws0[s] = A.w[2 + s][m * 2 + 0];
    ws1[s] = A.w[2 + s][m * 2 + 1];
    bsv[s] = A.bs[2 + s][m];
  }

  __shared__ float lds_buf[BPB][2][8];
  const int bbase = blockIdx.x * BPB;

  for (int bi = 0; bi < BPB; ++bi) {
    const int b = bbase + bi;
    const float2* xp = reinterpret_cast<const float2*>(A.x + (size_t)b * K0 + kb);
    const float2 xa = xp[0], xb = xp[1], xc = xp[2];
    const float xv[6] = {xa.x, xa.y, xb.x, xb.y, xc.x, xc.y};

    float acc0 = b0a, acc1 = b0b;
    #pragma unroll
    for (int j = 0; j < 6; ++j) {
      float tp = fmaf(p_ap1[j], xv[j], p_ap2[j]);
      float tm = fmaf(p_am1[j], xv[j], p_am2[j]);
      tp = fminf(fmaxf(tp, -60.0f), 60.0f);
      tm = fminf(fmaxf(tm, -60.0f), 60.0f);
      const float gp = __expf(tp);
      const float gm = __expf(tm);
      const float gz = p_g0[j];
      const float num = fmaf(50.0f, gp, fmaf(-70.0f, gm, -65.0f * gz));
      const float den = gp + gm + gz;
      const float s = num * __builtin_amdgcn_rcpf(den);
      if (j < 3) acc0 = fmaf(w0v[j], s, acc0);
      else       acc1 = fmaf(w0v[j], s, acc1);
    }
    acc0 = lrelu(acc0);
    acc1 = lrelu(acc1);
    float v = lrelu(fmaf(w1a, acc0, fmaf(w1b, acc1, b1v)));

    #pragma unroll
    for (int s = 0; s < 6; ++s) {
      const float u = __shfl_down(v, 32 >> s, 64);
      v = lrelu(fmaf(ws0[s], v, fmaf(ws1[s], u, bsv[s])));
    }
    if (l == 0) lds_buf[bi][r][c] = v;
  }
  __syncthreads();

  // finisher: levels 8..10 + root, one thread per batch row (fp32)
  if (tid < BPB) {
    const int b = bbase + tid;
    float o = A.root_b[0];
    #pragma unroll
    for (int rr = 0; rr < 2; ++rr) {
      float v8[8];
      #pragma unroll
      for (int q = 0; q < 8; ++q) v8[q] = lds_buf[tid][rr][q];
      float v4[4];
      #pragma unroll
      for (int n = 0; n < 4; ++n)
        v4[n] = lrelu(fmaf(A.w[8][(rr * 4 + n) * 2 + 0], v8[2 * n],
                      fmaf(A.w[8][(rr * 4 + n) * 2 + 1], v8[2 * n + 1],
                           A.bs[8][rr * 4 + n])));
      float v2[2];
      #pragma unroll
      for (int n = 0; n < 2; ++n)
        v2[n] = lrelu(fmaf(A.w[9][(rr * 2 + n) * 2 + 0], v4[2 * n],
                      fmaf(A.w[9][(rr * 2 + n) * 2 + 1], v4[2 * n + 1],
                           A.bs[9][rr * 2 + n])));
      const float v1 = lrelu(fmaf(A.w[10][rr * 2 + 0], v2[0],
                             fmaf(A.w[10][rr * 2 + 1], v2[1],
                                  A.bs[10][rr])));
      o = fmaf(A.root_w[rr], v1, o);
    }
    A.out[b] = o;
  }
}

extern "C" void kernel_launch(void* const* d_in, const int* in_sizes, int n_in,
                              void* d_out, int out_size, void* d_ws, size_t ws_size,
                              hipStream_t stream) {
  KtreeArgs A;
  A.x   = (const float*)d_in[0];
  A.ap1 = (const float*)d_in[1];
  A.ap2 = (const float*)d_in[2];
  A.am1 = (const float*)d_in[3];
  A.am2 = (const float*)d_in[4];
  A.g0  = (const float*)d_in[5];
  for (int i = 0; i < 11; ++i) {
    A.w[i]  = (const float*)d_in[6 + 2 * i];
    A.bs[i] = (const float*)d_in[7 + 2 * i];
  }
  A.root_w = (const float*)d_in[28];
  A.root_b = (const float*)d_in[29];
  A.out = (float*)d_out;

  const int grid = 8192 / BPB;   // 512 blocks x 1024 threads -> 2 blocks/CU
  hipLaunchKernelGGL(ktree_synapse_kernel, dim3(grid), dim3(BLOCK), 0, stream, A);
}

// Round 5
// 216.522 us; speedup vs baseline: 1.5478x; 1.5478x over previous
//
#include <hip/hip_runtime.h>

#define K0 3072
#define BPB 16            // batch rows per block (512 blocks -> 2 blocks/CU)
#define BLOCK 1024        // 16 waves: wave = (r<<3) | chunk

struct KtreeArgs {
  const float* x;
  const float* ap1; const float* ap2; const float* am1; const float* am2; const float* g0;
  const float* w[11];
  const float* bs[11];
  const float* root_w; const float* root_b;
  float* out;
};

__device__ __forceinline__ float lrelu(float v) {
  return v >= 0.0f ? v : 0.01f * v;
}

__global__ __launch_bounds__(BLOCK, 4) void ktree_synapse_kernel(KtreeArgs A) {
  const int tid = threadIdx.x;
  const int wv  = tid >> 6;        // 0..15
  const int l   = tid & 63;
  const int c   = wv & 7;          // k-chunk: K=8-level node index
  const int r   = wv >> 3;         // population 0/1

  // natural order: lane l owns K=512-level node c*64 + l -> coalesced x reads
  const int node512 = c * 64 + l;
  const int kb      = node512 * 6;

  // ---- per-lane param pointers (reloaded per row; L1/L2-resident) ----
  const int o_syn = r * K0 + kb;
  const float* p_ap1 = A.ap1 + o_syn;
  const float* p_ap2 = A.ap2 + o_syn;
  const float* p_am1 = A.am1 + o_syn;
  const float* p_am2 = A.am2 + o_syn;
  const float* p_g0  = A.g0  + o_syn;

  // persistent tree weights (registers, constant across rows)
  float w0v[6], b0a, b0b;
  {
    const int o = (r * 1024 + 2 * node512) * 3;
    #pragma unroll
    for (int j = 0; j < 6; ++j) w0v[j] = A.w[0][o + j];
    b0a = A.bs[0][r * 1024 + 2 * node512];
    b0b = A.bs[0][r * 1024 + 2 * node512 + 1];
  }
  float w1a, w1b, b1v;
  {
    const int n = r * 512 + node512;
    w1a = A.w[1][n * 2 + 0];
    w1b = A.w[1][n * 2 + 1];
    b1v = A.bs[1][n];
  }
  // levels 2..7: xor-butterfly steps s=0..5 (stride 1<<s), swapped-weight trick.
  // Before step s, lane l holds node c*(64>>s) + (l>>s) of level K=512>>s.
  float wso[6], wst[6], bsv[6];
  #pragma unroll
  for (int s = 0; s < 6; ++s) {
    const int mo  = c * (32 >> s) + (l >> (s + 1));   // output node within r
    const int idx = r * (256 >> s) + mo;
    const int odd = (l >> s) & 1;                     // own value is odd child?
    wso[s] = A.w[2 + s][idx * 2 + odd];
    wst[s] = A.w[2 + s][idx * 2 + (odd ^ 1)];
    bsv[s] = A.bs[2 + s][idx];
  }

  __shared__ float lds_buf[BPB][2][8];
  const int bbase = blockIdx.x * BPB;

  for (int bi = 0; bi < BPB; ++bi) {
    const int b = bbase + bi;
    const float2* xp = reinterpret_cast<const float2*>(A.x + (size_t)b * K0 + kb);
    const float2 xa = xp[0], xb = xp[1], xc = xp[2];
    const float xv[6] = {xa.x, xa.y, xb.x, xb.y, xc.x, xc.y};

    float acc0 = b0a, acc1 = b0b;
    #pragma unroll
    for (int j = 0; j < 6; ++j) {
      float tp = fmaf(p_ap1[j], xv[j], p_ap2[j]);
      float tm = fmaf(p_am1[j], xv[j], p_am2[j]);
      tp = fminf(fmaxf(tp, -60.0f), 60.0f);
      tm = fminf(fmaxf(tm, -60.0f), 60.0f);
      const float gp = __expf(tp);
      const float gm = __expf(tm);
      const float gz = p_g0[j];
      const float num = fmaf(50.0f, gp, fmaf(-70.0f, gm, -65.0f * gz));
      const float den = gp + gm + gz;
      const float s = num * __builtin_amdgcn_rcpf(den);
      if (j < 3) acc0 = fmaf(w0v[j], s, acc0);
      else       acc1 = fmaf(w0v[j], s, acc1);
    }
    acc0 = lrelu(acc0);
    acc1 = lrelu(acc1);
    float v = lrelu(fmaf(w1a, acc0, fmaf(w1b, acc1, b1v)));

    #pragma unroll
    for (int s = 0; s < 6; ++s) {
      const float u = __shfl_xor(v, 1 << s, 64);
      v = lrelu(fmaf(wso[s], v, fmaf(wst[s], u, bsv[s])));
    }
    if (l == 0) lds_buf[bi][r][c] = v;
  }
  __syncthreads();

  // finisher: levels 8..10 + root, one thread per batch row (fp32)
  if (tid < BPB) {
    const int b = bbase + tid;
    float o = A.root_b[0];
    #pragma unroll
    for (int rr = 0; rr < 2; ++rr) {
      float v8[8];
      #pragma unroll
      for (int q = 0; q < 8; ++q) v8[q] = lds_buf[tid][rr][q];
      float v4[4];
      #pragma unroll
      for (int n = 0; n < 4; ++n)
        v4[n] = lrelu(fmaf(A.w[8][(rr * 4 + n) * 2 + 0], v8[2 * n],
                      fmaf(A.w[8][(rr * 4 + n) * 2 + 1], v8[2 * n + 1],
                           A.bs[8][rr * 4 + n])));
      float v2[2];
      #pragma unroll
      for (int n = 0; n < 2; ++n)
        v2[n] = lrelu(fmaf(A.w[9][(rr * 2 + n) * 2 + 0], v4[2 * n],
                      fmaf(A.w[9][(rr * 2 + n) * 2 + 1], v4[2 * n + 1],
                           A.bs[9][rr * 2 + n])));
      const float v1 = lrelu(fmaf(A.w[10][rr * 2 + 0], v2[0],
                             fmaf(A.w[10][rr * 2 + 1], v2[1],
                                  A.bs[10][rr])));
      o = fmaf(A.root_w[rr], v1, o);
    }
    A.out[b] = o;
  }
}

extern "C" void kernel_launch(void* const* d_in, const int* in_sizes, int n_in,
                              void* d_out, int out_size, void* d_ws, size_t ws_size,
                              hipStream_t stream) {
  KtreeArgs A;
  A.x   = (const float*)d_in[0];
  A.ap1 = (const float*)d_in[1];
  A.ap2 = (const float*)d_in[2];
  A.am1 = (const float*)d_in[3];
  A.am2 = (const float*)d_in[4];
  A.g0  = (const float*)d_in[5];
  for (int i = 0; i < 11; ++i) {
    A.w[i]  = (const float*)d_in[6 + 2 * i];
    A.bs[i] = (const float*)d_in[7 + 2 * i];
  }
  A.root_w = (const float*)d_in[28];
  A.root_b = (const float*)d_in[29];
  A.out = (float*)d_out;

  const int grid = 8192 / BPB;   // 512 blocks x 1024 threads -> 2 blocks/CU
  hipLaunchKernelGGL(ktree_synapse_kernel, dim3(grid), dim3(BLOCK), 0, stream, A);
}